// Round 1
// baseline (25044.826 us; speedup 1.0000x reference)
//
#include <hip/hip_runtime.h>
#include <math.h>

static constexpr int V = 32000, B = 4, T = 1024, C = 1024, H = 16, NL = 8, HS = 64;
static constexpr int M = B * T; // 4096 rows of activations

// ---------------------------------------------------------------- embed
__global__ void k_embed(const int* __restrict__ idx, const float* __restrict__ tok,
                        const float* __restrict__ pos, float* __restrict__ x) {
  int g = blockIdx.x * blockDim.x + threadIdx.x; // over M*C/4
  if (g >= M * C / 4) return;
  int c4 = g & 255;  // C/4 = 256 float4 per row
  int bt = g >> 8;
  int t = bt & (T - 1);
  int row = idx[bt];
  float4 tv = *(const float4*)(tok + (size_t)row * C + c4 * 4);
  float4 pv = *(const float4*)(pos + (size_t)t * C + c4 * 4);
  float4 o;
  o.x = tv.x + pv.x; o.y = tv.y + pv.y; o.z = tv.z + pv.z; o.w = tv.w + pv.w;
  *(float4*)(x + (size_t)bt * C + c4 * 4) = o;
}

// ---------------------------------------------------------------- layernorm (one block per row, C=1024)
__global__ __launch_bounds__(256) void k_ln(const float* __restrict__ x, const float* __restrict__ g,
                                            const float* __restrict__ b, float* __restrict__ y) {
  int row = blockIdx.x, tid = threadIdx.x;
  float4 v = ((const float4*)(x + (size_t)row * C))[tid];
  float s = v.x + v.y + v.z + v.w;
  float ss = v.x * v.x + v.y * v.y + v.z * v.z + v.w * v.w;
  for (int off = 32; off > 0; off >>= 1) {
    s += __shfl_down(s, off);
    ss += __shfl_down(ss, off);
  }
  __shared__ float sb[4], qb[4];
  int wid = tid >> 6;
  if ((tid & 63) == 0) { sb[wid] = s; qb[wid] = ss; }
  __syncthreads();
  float st = sb[0] + sb[1] + sb[2] + sb[3];
  float qt = qb[0] + qb[1] + qb[2] + qb[3];
  float mean = st * (1.0f / C);
  float var = qt * (1.0f / C) - mean * mean;
  float rstd = rsqrtf(var + 1e-5f);
  float4 gv = ((const float4*)g)[tid];
  float4 bv = ((const float4*)b)[tid];
  float4 o;
  o.x = (v.x - mean) * rstd * gv.x + bv.x;
  o.y = (v.y - mean) * rstd * gv.y + bv.y;
  o.z = (v.z - mean) * rstd * gv.z + bv.z;
  o.w = (v.w - mean) * rstd * gv.w + bv.w;
  ((float4*)(y + (size_t)row * C))[tid] = o;
}

// ---------------------------------------------------------------- pack Wq|Wk|Wv (L,H,C,HS) -> [C, 3072]
__global__ void k_pack_qkv(const float* __restrict__ Wq, const float* __restrict__ Wk,
                           const float* __restrict__ Wv, float* __restrict__ wp) {
  int g = blockIdx.x * blockDim.x + threadIdx.x; // over C*3072/4
  if (g >= C * 3072 / 4) return;
  int col4 = g % 768;
  int c = g / 768;
  int j = col4 * 4;
  int sel = j >> 10;
  int within = j & 1023;
  int h = within >> 6, s0 = within & 63;
  const float* W = sel == 0 ? Wq : (sel == 1 ? Wk : Wv);
  float4 v = *(const float4*)(W + ((size_t)h * C + c) * HS + s0);
  *(float4*)(wp + (size_t)c * 3072 + j) = v;
}

// ---------------------------------------------------------------- bias sum over heads: bs[c] = sum_h Ph_b[h][c]
__global__ void k_bsum(const float* __restrict__ phb, float* __restrict__ bs) {
  int c = blockIdx.x * blockDim.x + threadIdx.x;
  if (c < C) {
    float s = 0.0f;
    for (int h = 0; h < H; ++h) s += phb[(size_t)h * C + c];
    bs[c] = s;
  }
}

// ---------------------------------------------------------------- generic fp32 GEMM: Cm = A[M,K] @ Bm[K,N] (+bias)(+gelu)(+res)
template <int BIAS, int GELU, int RES>
__global__ __launch_bounds__(256) void k_gemm(const float* __restrict__ A, const float* __restrict__ Bm,
                                              float* __restrict__ Cm, const float* __restrict__ bias,
                                              const float* __restrict__ res, int N, int K) {
  __shared__ float As[16][68]; // As[k][m] (A^T tile)
  __shared__ float Bs[16][68]; // Bs[k][n]
  int bm = blockIdx.y * 64, bn = blockIdx.x * 64;
  int tid = threadIdx.x;
  int ty = tid >> 4, tx = tid & 15;
  float acc[4][4] = {};
  int ar = tid >> 2, akq = (tid & 3) * 4;
  int bkr = tid >> 4, bnq = (tid & 15) * 4;
  for (int k0 = 0; k0 < K; k0 += 16) {
    __syncthreads();
    float4 a = *(const float4*)(A + (size_t)(bm + ar) * K + k0 + akq);
    As[akq + 0][ar] = a.x;
    As[akq + 1][ar] = a.y;
    As[akq + 2][ar] = a.z;
    As[akq + 3][ar] = a.w;
    *(float4*)&Bs[bkr][bnq] = *(const float4*)(Bm + (size_t)(k0 + bkr) * N + bn + bnq);
    __syncthreads();
#pragma unroll
    for (int k = 0; k < 16; ++k) {
      float4 av = *(const float4*)&As[k][ty * 4];
      float4 bv = *(const float4*)&Bs[k][tx * 4];
      float aa[4] = {av.x, av.y, av.z, av.w};
      float bb[4] = {bv.x, bv.y, bv.z, bv.w};
#pragma unroll
      for (int i = 0; i < 4; ++i)
#pragma unroll
        for (int j = 0; j < 4; ++j) acc[i][j] = fmaf(aa[i], bb[j], acc[i][j]);
    }
  }
#pragma unroll
  for (int i = 0; i < 4; ++i) {
    int row = bm + ty * 4 + i;
#pragma unroll
    for (int j = 0; j < 4; ++j) {
      int col = bn + tx * 4 + j;
      float v = acc[i][j];
      if (BIAS) v += bias[col];
      if (GELU) v = 0.5f * v * (1.0f + erff(v * 0.70710678118f));
      if (RES) v += res[(size_t)row * N + col];
      Cm[(size_t)row * N + col] = v;
    }
  }
}

// ---------------------------------------------------------------- flash attention fp32
// qkv: [M, 3072] (q at col h*64+s, k at 1024+..., v at 2048+...), o: [M, 1024]
__global__ __launch_bounds__(256) void k_attn(const float* __restrict__ qkv, float* __restrict__ o) {
  int qi = blockIdx.x, bh = blockIdx.y;
  int b = bh >> 4, h = bh & 15;
  int tid = threadIdx.x;
  __shared__ float Qs[64][68];
  __shared__ float Ks[32][68];
  __shared__ float Vs[32][68];
  __shared__ float Ss[64][33];
  __shared__ float mrow[64], lrow[64], arow[64];
  // load Q tile [64 x 64]
  {
    int r = tid >> 2;
    int f0 = (tid & 3) * 4;
#pragma unroll
    for (int it = 0; it < 4; ++it) {
      int f = f0 + it;
      *(float4*)&Qs[r][f * 4] =
          *(const float4*)(qkv + ((size_t)(b * T + qi * 64 + r)) * 3072 + h * 64 + f * 4);
    }
  }
  if (tid < 64) { mrow[tid] = -1e30f; lrow[tid] = 0.0f; }
  float O[16] = {};
  int t = tid >> 2;         // owned output row
  int sb = (tid & 3) * 16;  // owned output col base
  int nk = (qi + 1) * 2;    // K tiles of 32 covering causal range
  for (int kt = 0; kt < nk; ++kt) {
    int u0 = kt * 32;
    __syncthreads();
    {
      int r = tid >> 3;
      int f0 = (tid & 7) * 2;
#pragma unroll
      for (int it = 0; it < 2; ++it) {
        int f = f0 + it;
        size_t rowoff = ((size_t)(b * T + u0 + r)) * 3072 + h * 64 + f * 4;
        *(float4*)&Ks[r][f * 4] = *(const float4*)(qkv + 1024 + rowoff);
        *(float4*)&Vs[r][f * 4] = *(const float4*)(qkv + 2048 + rowoff);
      }
    }
    __syncthreads();
    // S = scale * Q K^T with causal mask
#pragma unroll
    for (int rep = 0; rep < 8; ++rep) {
      int idx2 = tid + rep * 256;
      int tt = idx2 >> 5, uu = idx2 & 31;
      float dot = 0.0f;
#pragma unroll
      for (int s = 0; s < 64; s += 4) {
        float4 qv = *(const float4*)&Qs[tt][s];
        float4 kv = *(const float4*)&Ks[uu][s];
        dot = fmaf(qv.x, kv.x, dot);
        dot = fmaf(qv.y, kv.y, dot);
        dot = fmaf(qv.z, kv.z, dot);
        dot = fmaf(qv.w, kv.w, dot);
      }
      dot *= 0.03125f;  // scale = C^-0.5 = 1/32 (NOT head_size^-0.5)
      if (u0 + uu > qi * 64 + tt) dot = -1e30f;
      Ss[tt][uu] = dot;
    }
    __syncthreads();
    // online softmax stats per row
    if (tid < 64) {
      float mold = mrow[tid];
      float mx = mold;
      for (int u = 0; u < 32; ++u) mx = fmaxf(mx, Ss[tid][u]);
      float al = __expf(mold - mx);
      float sum = 0.0f;
      for (int u = 0; u < 32; ++u) {
        float p = __expf(Ss[tid][u] - mx);
        Ss[tid][u] = p;
        sum += p;
      }
      mrow[tid] = mx;
      arow[tid] = al;
      lrow[tid] = lrow[tid] * al + sum;
    }
    __syncthreads();
    float al = arow[t];
#pragma unroll
    for (int j = 0; j < 16; ++j) O[j] *= al;
    for (int u = 0; u < 32; ++u) {
      float p = Ss[t][u];
#pragma unroll
      for (int j = 0; j < 16; ++j) O[j] = fmaf(p, Vs[u][sb + j], O[j]);
    }
  }
  __syncthreads();
  float inv = 1.0f / lrow[t];
  size_t orow = ((size_t)(b * T + qi * 64 + t)) * 1024 + h * 64 + sb;
#pragma unroll
  for (int j = 0; j < 16; ++j) o[orow + j] = O[j] * inv;
}

// ---------------------------------------------------------------- launch
extern "C" void kernel_launch(void* const* d_in, const int* in_sizes, int n_in,
                              void* d_out, int out_size, void* d_ws, size_t ws_size,
                              hipStream_t stream) {
  const int* idx = (const int*)d_in[0];
  const float* tok = (const float*)d_in[1];
  const float* pos = (const float*)d_in[2];
  const float* Wq = (const float*)d_in[3];
  const float* Wk = (const float*)d_in[4];
  const float* Wv = (const float*)d_in[5];
  const float* Phw = (const float*)d_in[6];
  const float* Phb = (const float*)d_in[7];
  const float* Pmw = (const float*)d_in[8];
  const float* Pmb = (const float*)d_in[9];
  const float* ln1g = (const float*)d_in[10];
  const float* ln1b = (const float*)d_in[11];
  const float* ln2g = (const float*)d_in[12];
  const float* ln2b = (const float*)d_in[13];
  const float* W1 = (const float*)d_in[14];
  const float* b1 = (const float*)d_in[15];
  const float* W2 = (const float*)d_in[16];
  const float* b2 = (const float*)d_in[17];
  const float* lnfg = (const float*)d_in[18];
  const float* lnfb = (const float*)d_in[19];
  const float* headw = (const float*)d_in[20];
  const float* headb = (const float*)d_in[21];
  float* out = (float*)d_out;

  float* ws = (float*)d_ws;
  float* x = ws;                      // [M, C]
  float* xn = x + (size_t)M * C;      // [M, C]
  float* ob = xn + (size_t)M * C;     // [M, C] attention output
  float* sa = ob + (size_t)M * C;     // [M, C]
  float* R1 = sa + (size_t)M * C;     // max(qkv [M,3072], mlp hidden [M,4C]) = [M, 4C]
  float* wpack = R1 + (size_t)M * 4 * C;  // [C, 3072]
  float* bsum = wpack + (size_t)C * 3072; // [C]

  // embed
  k_embed<<<(M * C / 4 + 255) / 256, 256, 0, stream>>>(idx, tok, pos, x);

  for (int l = 0; l < NL; ++l) {
    const float* wq = Wq + (size_t)l * H * C * HS;
    const float* wk = Wk + (size_t)l * H * C * HS;
    const float* wv = Wv + (size_t)l * H * C * HS;

    // ln1
    k_ln<<<M, 256, 0, stream>>>(x, ln1g + (size_t)l * C, ln1b + (size_t)l * C, xn);
    // pack qkv weights -> [C, 3072]
    k_pack_qkv<<<(C * 3072 / 4 + 255) / 256, 256, 0, stream>>>(wq, wk, wv, wpack);
    // qkv = xn @ wpack   [M, 3072]
    k_gemm<0, 0, 0><<<dim3(3072 / 64, M / 64), 256, 0, stream>>>(xn, wpack, R1, nullptr, nullptr, 3072, C);
    // attention
    k_attn<<<dim3(T / 64, B * H), 256, 0, stream>>>(R1, ob);
    // bias sum over heads
    k_bsum<<<(C + 255) / 256, 256, 0, stream>>>(Phb + (size_t)l * H * C, bsum);
    // sa_pre = ob @ Ph_w[l] + bsum    (Ph_w[l] is row-major [H*HS, C])
    k_gemm<1, 0, 0><<<dim3(C / 64, M / 64), 256, 0, stream>>>(
        ob, Phw + (size_t)l * H * HS * C, sa, bsum, nullptr, C, C);
    // x = x + sa_pre @ Pm_w[l] + Pm_b[l]
    k_gemm<1, 0, 1><<<dim3(C / 64, M / 64), 256, 0, stream>>>(
        sa, Pmw + (size_t)l * C * C, x, Pmb + (size_t)l * C, x, C, C);
    // ln2
    k_ln<<<M, 256, 0, stream>>>(x, ln2g + (size_t)l * C, ln2b + (size_t)l * C, xn);
    // h = gelu(xn @ W1 + b1)   [M, 4C]
    k_gemm<1, 1, 0><<<dim3(4 * C / 64, M / 64), 256, 0, stream>>>(
        xn, W1 + (size_t)l * C * 4 * C, R1, b1 + (size_t)l * 4 * C, nullptr, 4 * C, C);
    // x = x + h @ W2 + b2
    k_gemm<1, 0, 1><<<dim3(C / 64, M / 64), 256, 0, stream>>>(
        R1, W2 + (size_t)l * 4 * C * C, x, b2 + (size_t)l * C, x, C, 4 * C);
  }

  // final LN + head
  k_ln<<<M, 256, 0, stream>>>(x, lnfg, lnfb, xn);
  k_gemm<1, 0, 0><<<dim3(V / 64, M / 64), 256, 0, stream>>>(xn, headw, out, headb, nullptr, V, C);
}

// Round 3
// 11993.676 us; speedup vs baseline: 2.0882x; 2.0882x over previous
//
#include <hip/hip_runtime.h>
#include <hip/hip_bf16.h>
#include <math.h>

static constexpr int V = 32000, B = 4, T = 1024, C = 1024, H = 16, NL = 8, HS = 64;
static constexpr int M = B * T; // 4096 rows of activations

typedef __bf16 bf16x8 __attribute__((ext_vector_type(8)));
typedef float f32x4 __attribute__((ext_vector_type(4)));
typedef unsigned short u16x8 __attribute__((ext_vector_type(8)));

__device__ inline float bf2f(unsigned short u) {
  union { unsigned int i; float f; } c;
  c.i = ((unsigned int)u) << 16;
  return c.f;
}

// ---------------------------------------------------------------- embed
__global__ void k_embed(const int* __restrict__ idx, const float* __restrict__ tok,
                        const float* __restrict__ pos, float* __restrict__ x) {
  int g = blockIdx.x * blockDim.x + threadIdx.x; // over M*C/4
  if (g >= M * C / 4) return;
  int c4 = g & 255;  // C/4 = 256 float4 per row
  int bt = g >> 8;
  int t = bt & (T - 1);
  int row = idx[bt];
  float4 tv = *(const float4*)(tok + (size_t)row * C + c4 * 4);
  float4 pv = *(const float4*)(pos + (size_t)t * C + c4 * 4);
  float4 o;
  o.x = tv.x + pv.x; o.y = tv.y + pv.y; o.z = tv.z + pv.z; o.w = tv.w + pv.w;
  *(float4*)(x + (size_t)bt * C + c4 * 4) = o;
}

// ---------------------------------------------------------------- layernorm fp32 -> bf16
__global__ __launch_bounds__(256) void k_ln_bf(const float* __restrict__ x, const float* __restrict__ g,
                                               const float* __restrict__ b, __hip_bfloat16* __restrict__ y) {
  int row = blockIdx.x, tid = threadIdx.x;
  float4 v = ((const float4*)(x + (size_t)row * C))[tid];
  float s = v.x + v.y + v.z + v.w;
  float ss = v.x * v.x + v.y * v.y + v.z * v.z + v.w * v.w;
  for (int off = 32; off > 0; off >>= 1) {
    s += __shfl_down(s, off);
    ss += __shfl_down(ss, off);
  }
  __shared__ float sb[4], qb[4];
  int wid = tid >> 6;
  if ((tid & 63) == 0) { sb[wid] = s; qb[wid] = ss; }
  __syncthreads();
  float st = sb[0] + sb[1] + sb[2] + sb[3];
  float qt = qb[0] + qb[1] + qb[2] + qb[3];
  float mean = st * (1.0f / C);
  float var = qt * (1.0f / C) - mean * mean;
  float rstd = rsqrtf(var + 1e-5f);
  float4 gv = ((const float4*)g)[tid];
  float4 bv = ((const float4*)b)[tid];
  union { __hip_bfloat16 h[4]; ushort4 u; } pk;
  pk.h[0] = __float2bfloat16((v.x - mean) * rstd * gv.x + bv.x);
  pk.h[1] = __float2bfloat16((v.y - mean) * rstd * gv.y + bv.y);
  pk.h[2] = __float2bfloat16((v.z - mean) * rstd * gv.z + bv.z);
  pk.h[3] = __float2bfloat16((v.w - mean) * rstd * gv.w + bv.w);
  *(ushort4*)(y + (size_t)row * C + tid * 4) = pk.u;
}

// ---------------------------------------------------------------- generic transpose+convert: in [K][N] f32 -> out [N][K] bf16
__global__ __launch_bounds__(256) void k_transp(const float* __restrict__ in, __hip_bfloat16* __restrict__ out,
                                                int K, int N) {
  __shared__ float t[64][65];
  int n0 = blockIdx.x * 64, k0 = blockIdx.y * 64;
  int tx = threadIdx.x & 15, ty = threadIdx.x >> 4;
#pragma unroll
  for (int i = 0; i < 64; i += 16) {
    float4 v = *(const float4*)(in + (size_t)(k0 + ty + i) * N + n0 + tx * 4);
    t[ty + i][tx * 4 + 0] = v.x;
    t[ty + i][tx * 4 + 1] = v.y;
    t[ty + i][tx * 4 + 2] = v.z;
    t[ty + i][tx * 4 + 3] = v.w;
  }
  __syncthreads();
#pragma unroll
  for (int i = 0; i < 64; i += 16) {
    int n = ty + i;
    union { __hip_bfloat16 h[4]; ushort4 u; } pk;
#pragma unroll
    for (int j = 0; j < 4; ++j) pk.h[j] = __float2bfloat16(t[tx * 4 + j][n]);
    *(ushort4*)(out + (size_t)(n0 + n) * K + k0 + tx * 4) = pk.u;
  }
}

// ---------------------------------------------------------------- qkv weights (H,C,HS) x3 -> [3072][1024] bf16 (row = sel*1024+h*64+s)
__global__ __launch_bounds__(256) void k_prep_qkv(const float* __restrict__ Wq, const float* __restrict__ Wk,
                                                  const float* __restrict__ Wv, __hip_bfloat16* __restrict__ out) {
  int z = blockIdx.y;  // sel*16 + h
  int sel = z >> 4, h = z & 15;
  const float* W = sel == 0 ? Wq : (sel == 1 ? Wk : Wv);
  const float* in = W + (size_t)h * C * HS;                      // [1024][64]
  __hip_bfloat16* o = out + ((size_t)sel * 1024 + h * 64) * C;   // [64][1024]
  __shared__ float t[64][65];
  int k0 = blockIdx.x * 64;
  int tx = threadIdx.x & 15, ty = threadIdx.x >> 4;
#pragma unroll
  for (int i = 0; i < 64; i += 16) {
    float4 v = *(const float4*)(in + (size_t)(k0 + ty + i) * HS + tx * 4);
    t[ty + i][tx * 4 + 0] = v.x;
    t[ty + i][tx * 4 + 1] = v.y;
    t[ty + i][tx * 4 + 2] = v.z;
    t[ty + i][tx * 4 + 3] = v.w;
  }
  __syncthreads();
#pragma unroll
  for (int i = 0; i < 64; i += 16) {
    int n = ty + i;
    union { __hip_bfloat16 h4[4]; ushort4 u; } pk;
#pragma unroll
    for (int j = 0; j < 4; ++j) pk.h4[j] = __float2bfloat16(t[tx * 4 + j][n]);
    *(ushort4*)(o + (size_t)n * C + k0 + tx * 4) = pk.u;
  }
}

// ---------------------------------------------------------------- bias sum over heads
__global__ void k_bsum(const float* __restrict__ phb, float* __restrict__ bs) {
  int c = blockIdx.x * blockDim.x + threadIdx.x;
  if (c < C) {
    float s = 0.0f;
    for (int h = 0; h < H; ++h) s += phb[(size_t)h * C + c];
    bs[c] = s;
  }
}

// ---------------------------------------------------------------- bf16 MFMA GEMM (m97 structure)
// A [M,K] bf16 row-major, Bt [N,K] bf16 row-major; Cm = A @ Bt^T. 128x128 tile, BK=32, 4 waves.
template <int BIAS, int GELU, int RES, int OUTBF>
__global__ __launch_bounds__(256) void k_gemm_bf(const __hip_bfloat16* __restrict__ A,
                                                 const __hip_bfloat16* __restrict__ Bt,
                                                 void* Cout, const float* __restrict__ bias,
                                                 const float* res, int N, int K) {
  __shared__ __align__(16) __hip_bfloat16 As[128 * 32];
  __shared__ __align__(16) __hip_bfloat16 Bs[128 * 32];
  int bm = blockIdx.y * 128, bn = blockIdx.x * 128;
  int tid = threadIdx.x;
  int w = tid >> 6, l = tid & 63;
  int wr = (w >> 1) * 64, wc = (w & 1) * 64;
  int lr = l >> 2;          // staging: row within 16-row segment
  int lk = (l & 3) * 8;     // staging: k offset
  int fr = l & 15;          // fragment row/col within 16
  int fk = (l >> 4) * 8;    // fragment k offset
  const __hip_bfloat16* Ag = A + (size_t)bm * K;
  const __hip_bfloat16* Bg = Bt + (size_t)bn * K;
  f32x4 acc[4][4];
#pragma unroll
  for (int m = 0; m < 4; ++m)
#pragma unroll
    for (int n = 0; n < 4; ++n) acc[m][n] = (f32x4){0.f, 0.f, 0.f, 0.f};

  for (int k0 = 0; k0 < K; k0 += 32) {
    __syncthreads();
#pragma unroll
    for (int i = 0; i < 2; ++i) {
      int seg = w * 2 + i;
      int r = seg * 16 + lr;
      __builtin_amdgcn_global_load_lds(
          (const __attribute__((address_space(1))) void*)(Ag + (size_t)r * K + k0 + lk),
          (__attribute__((address_space(3))) void*)(As + seg * 512), 16, 0, 0);
      __builtin_amdgcn_global_load_lds(
          (const __attribute__((address_space(1))) void*)(Bg + (size_t)r * K + k0 + lk),
          (__attribute__((address_space(3))) void*)(Bs + seg * 512), 16, 0, 0);
    }
    __syncthreads();
    bf16x8 af[4], bfr[4];
#pragma unroll
    for (int m = 0; m < 4; ++m) af[m] = *(const bf16x8*)(As + ((size_t)(wr + m * 16 + fr)) * 32 + fk);
#pragma unroll
    for (int n = 0; n < 4; ++n) bfr[n] = *(const bf16x8*)(Bs + ((size_t)(wc + n * 16 + fr)) * 32 + fk);
#pragma unroll
    for (int m = 0; m < 4; ++m)
#pragma unroll
      for (int n = 0; n < 4; ++n)
        acc[m][n] = __builtin_amdgcn_mfma_f32_16x16x32_bf16(af[m], bfr[n], acc[m][n], 0, 0, 0);
  }
  // epilogue: C/D layout col=lane&15, row=(lane>>4)*4+reg
  int crow0 = (l >> 4) * 4;
  int ccol = l & 15;
#pragma unroll
  for (int m = 0; m < 4; ++m) {
    int row = bm + wr + m * 16 + crow0;
#pragma unroll
    for (int n = 0; n < 4; ++n) {
      int col = bn + wc + n * 16 + ccol;
      float bv = BIAS ? bias[col] : 0.0f;
#pragma unroll
      for (int r = 0; r < 4; ++r) {
        float v = acc[m][n][r] + bv;
        if (GELU) v = 0.5f * v * (1.0f + erff(v * 0.70710678118f));
        if (RES) v += res[(size_t)(row + r) * N + col];
        if (OUTBF)
          ((__hip_bfloat16*)Cout)[(size_t)(row + r) * N + col] = __float2bfloat16(v);
        else
          ((float*)Cout)[(size_t)(row + r) * N + col] = v;
      }
    }
  }
}

// ---------------------------------------------------------------- flash attention (bf16 in/out, fp32 compute)
// qkv: [M, 3072] bf16 (q at col h*64+s, k at 1024+..., v at 2048+...), o: [M, 1024] bf16
__global__ __launch_bounds__(256) void k_attn(const __hip_bfloat16* __restrict__ qkv,
                                              __hip_bfloat16* __restrict__ o) {
  int qi = blockIdx.x, bh = blockIdx.y;
  int b = bh >> 4, h = bh & 15;
  int tid = threadIdx.x;
  __shared__ float Qs[64][68];
  __shared__ float Ks[32][68];
  __shared__ float Vs[32][68];
  __shared__ float Ss[64][33];
  __shared__ float mrow[64], lrow[64], arow[64];
  // load Q tile [64 x 64]
#pragma unroll
  for (int it = 0; it < 2; ++it) {
    int idx2 = tid + it * 256;
    int r = idx2 >> 3, c8 = idx2 & 7;
    u16x8 qv = *(const u16x8*)(qkv + ((size_t)(b * T + qi * 64 + r)) * 3072 + h * 64 + c8 * 8);
#pragma unroll
    for (int j = 0; j < 8; ++j) Qs[r][c8 * 8 + j] = bf2f(qv[j]);
  }
  if (tid < 64) { mrow[tid] = -1e30f; lrow[tid] = 0.0f; }
  float O[16] = {};
  int t = tid >> 2;
  int sb = (tid & 3) * 16;
  int nk = (qi + 1) * 2;
  for (int kt = 0; kt < nk; ++kt) {
    int u0 = kt * 32;
    __syncthreads();
    {
      int r = tid >> 3, c8 = tid & 7;
      size_t rowoff = ((size_t)(b * T + u0 + r)) * 3072 + h * 64 + c8 * 8;
      u16x8 kv = *(const u16x8*)(qkv + 1024 + rowoff);
      u16x8 vv = *(const u16x8*)(qkv + 2048 + rowoff);
#pragma unroll
      for (int j = 0; j < 8; ++j) {
        Ks[r][c8 * 8 + j] = bf2f(kv[j]);
        Vs[r][c8 * 8 + j] = bf2f(vv[j]);
      }
    }
    __syncthreads();
#pragma unroll
    for (int rep = 0; rep < 8; ++rep) {
      int idx2 = tid + rep * 256;
      int tt = idx2 >> 5, uu = idx2 & 31;
      float dot = 0.0f;
#pragma unroll
      for (int s = 0; s < 64; s += 4) {
        float4 qv = *(const float4*)&Qs[tt][s];
        float4 kv = *(const float4*)&Ks[uu][s];
        dot = fmaf(qv.x, kv.x, dot);
        dot = fmaf(qv.y, kv.y, dot);
        dot = fmaf(qv.z, kv.z, dot);
        dot = fmaf(qv.w, kv.w, dot);
      }
      dot *= 0.03125f;  // scale = C^-0.5 = 1/32 (NOT head_size^-0.5)
      if (u0 + uu > qi * 64 + tt) dot = -1e30f;
      Ss[tt][uu] = dot;
    }
    __syncthreads();
    if (tid < 64) {
      float mold = mrow[tid];
      float mx = mold;
      for (int u = 0; u < 32; ++u) mx = fmaxf(mx, Ss[tid][u]);
      float al = __expf(mold - mx);
      float sum = 0.0f;
      for (int u = 0; u < 32; ++u) {
        float p = __expf(Ss[tid][u] - mx);
        Ss[tid][u] = p;
        sum += p;
      }
      mrow[tid] = mx;
      arow[tid] = al;
      lrow[tid] = lrow[tid] * al + sum;
    }
    __syncthreads();
    float al = arow[t];
#pragma unroll
    for (int j = 0; j < 16; ++j) O[j] *= al;
    for (int u = 0; u < 32; ++u) {
      float p = Ss[t][u];
#pragma unroll
      for (int j = 0; j < 16; ++j) O[j] = fmaf(p, Vs[u][sb + j], O[j]);
    }
  }
  __syncthreads();
  float inv = 1.0f / lrow[t];
  size_t orow = ((size_t)(b * T + qi * 64 + t)) * 1024 + h * 64 + sb;
#pragma unroll
  for (int j = 0; j < 16; ++j) o[orow + j] = __float2bfloat16(O[j] * inv);
}

// ---------------------------------------------------------------- launch
extern "C" void kernel_launch(void* const* d_in, const int* in_sizes, int n_in,
                              void* d_out, int out_size, void* d_ws, size_t ws_size,
                              hipStream_t stream) {
  const int* idx = (const int*)d_in[0];
  const float* tok = (const float*)d_in[1];
  const float* pos = (const float*)d_in[2];
  const float* Wq = (const float*)d_in[3];
  const float* Wk = (const float*)d_in[4];
  const float* Wv = (const float*)d_in[5];
  const float* Phw = (const float*)d_in[6];
  const float* Phb = (const float*)d_in[7];
  const float* Pmw = (const float*)d_in[8];
  const float* Pmb = (const float*)d_in[9];
  const float* ln1g = (const float*)d_in[10];
  const float* ln1b = (const float*)d_in[11];
  const float* ln2g = (const float*)d_in[12];
  const float* ln2b = (const float*)d_in[13];
  const float* W1 = (const float*)d_in[14];
  const float* b1 = (const float*)d_in[15];
  const float* W2 = (const float*)d_in[16];
  const float* b2 = (const float*)d_in[17];
  const float* lnfg = (const float*)d_in[18];
  const float* lnfb = (const float*)d_in[19];
  const float* headw = (const float*)d_in[20];
  const float* headb = (const float*)d_in[21];
  float* out = (float*)d_out;

  // Workspace layout (peak ~109 MB; Round-1's 140 MB footprint is proven safe):
  //   x (fp32 residual) | bsum | [qkvb ob sa hb wt] (per-layer, contiguous 84MB) | xn
  // The head-weight transpose (64 MB) aliases the contiguous per-layer region,
  // which is entirely dead by the time the head runs; xn sits after it so the
  // final LN output survives.
  char* p = (char*)d_ws;
  float* x = (float*)p;                       p += (size_t)M * C * 4;
  float* bsumv = (float*)p;                   p += (size_t)C * 4;
  char* layer_region = p;
  __hip_bfloat16* qkvb = (__hip_bfloat16*)p;  p += (size_t)M * 3072 * 2;
  __hip_bfloat16* ob = (__hip_bfloat16*)p;    p += (size_t)M * C * 2;
  __hip_bfloat16* sa = (__hip_bfloat16*)p;    p += (size_t)M * C * 2;
  __hip_bfloat16* hb = (__hip_bfloat16*)p;    p += (size_t)M * 4 * C * 2;
  __hip_bfloat16* wt = (__hip_bfloat16*)p;    p += (size_t)4 * C * C * 2;  // per-layer weight scratch
  __hip_bfloat16* xn = (__hip_bfloat16*)p;    p += (size_t)M * C * 2;
  __hip_bfloat16* wt_head = (__hip_bfloat16*)layer_region;  // [V,C] bf16 = 64MB, aliases dead buffers

  k_embed<<<(M * C / 4 + 255) / 256, 256, 0, stream>>>(idx, tok, pos, x);

  for (int l = 0; l < NL; ++l) {
    // ln1 -> xn (bf16)
    k_ln_bf<<<M, 256, 0, stream>>>(x, ln1g + (size_t)l * C, ln1b + (size_t)l * C, xn);
    // qkv weights -> wt [3072][1024]
    k_prep_qkv<<<dim3(16, 48), 256, 0, stream>>>(Wq + (size_t)l * H * C * HS, Wk + (size_t)l * H * C * HS,
                                                 Wv + (size_t)l * H * C * HS, wt);
    // qkv = xn @ wt^T -> bf16 [M,3072]
    k_gemm_bf<0, 0, 0, 1><<<dim3(3072 / 128, M / 128), 256, 0, stream>>>(xn, wt, qkvb, nullptr, nullptr, 3072, C);
    // attention -> ob (bf16)
    k_attn<<<dim3(T / 64, B * H), 256, 0, stream>>>(qkvb, ob);
    // per-head proj bias summed over heads
    k_bsum<<<(C + 255) / 256, 256, 0, stream>>>(Phb + (size_t)l * H * C, bsumv);
    // Ph_w [1024,1024] -> wt^T
    k_transp<<<dim3(16, 16), 256, 0, stream>>>(Phw + (size_t)l * H * HS * C, wt, C, C);
    // sa = ob @ Phw + bsum -> bf16
    k_gemm_bf<1, 0, 0, 1><<<dim3(C / 128, M / 128), 256, 0, stream>>>(ob, wt, sa, bsumv, nullptr, C, C);
    // Pm_w -> wt^T
    k_transp<<<dim3(16, 16), 256, 0, stream>>>(Pmw + (size_t)l * C * C, wt, C, C);
    // x = x + sa @ Pmw + Pmb  (fp32 residual)
    k_gemm_bf<1, 0, 1, 0><<<dim3(C / 128, M / 128), 256, 0, stream>>>(sa, wt, x, Pmb + (size_t)l * C, x, C, C);
    // ln2 -> xn
    k_ln_bf<<<M, 256, 0, stream>>>(x, ln2g + (size_t)l * C, ln2b + (size_t)l * C, xn);
    // W1 [1024,4096] -> wt^T
    k_transp<<<dim3(64, 16), 256, 0, stream>>>(W1 + (size_t)l * C * 4 * C, wt, C, 4 * C);
    // h = gelu(xn @ W1 + b1) -> bf16 [M,4096]
    k_gemm_bf<1, 1, 0, 1><<<dim3(4 * C / 128, M / 128), 256, 0, stream>>>(xn, wt, hb, b1 + (size_t)l * 4 * C, nullptr, 4 * C, C);
    // W2 [4096,1024] -> wt^T
    k_transp<<<dim3(16, 64), 256, 0, stream>>>(W2 + (size_t)l * 4 * C * C, wt, 4 * C, C);
    // x = x + h @ W2 + b2
    k_gemm_bf<1, 0, 1, 0><<<dim3(C / 128, M / 128), 256, 0, stream>>>(hb, wt, x, b2 + (size_t)l * C, x, C, 4 * C);
  }

  // final LN + head (head weight transpose reuses the dead per-layer region)
  k_ln_bf<<<M, 256, 0, stream>>>(x, lnfg, lnfb, xn);
  k_transp<<<dim3(500, 16), 256, 0, stream>>>(headw, wt_head, C, V);
  k_gemm_bf<1, 0, 0, 0><<<dim3(V / 128, M / 128), 256, 0, stream>>>(xn, wt_head, out, headb, nullptr, V, C);
}

// Round 4
// 3694.330 us; speedup vs baseline: 6.7793x; 3.2465x over previous
//
#include <hip/hip_runtime.h>
#include <hip/hip_bf16.h>
#include <math.h>

static constexpr int V = 32000, B = 4, T = 1024, C = 1024, H = 16, NL = 8, HS = 64;
static constexpr int M = B * T; // 4096 rows of activations

typedef __bf16 bf16x8 __attribute__((ext_vector_type(8)));
typedef __bf16 bf16x4 __attribute__((ext_vector_type(4)));
typedef float f32x4 __attribute__((ext_vector_type(4)));

// ---------------------------------------------------------------- embed
__global__ void k_embed(const int* __restrict__ idx, const float* __restrict__ tok,
                        const float* __restrict__ pos, float* __restrict__ x) {
  int g = blockIdx.x * blockDim.x + threadIdx.x; // over M*C/4
  if (g >= M * C / 4) return;
  int c4 = g & 255;  // C/4 = 256 float4 per row
  int bt = g >> 8;
  int t = bt & (T - 1);
  int row = idx[bt];
  float4 tv = *(const float4*)(tok + (size_t)row * C + c4 * 4);
  float4 pv = *(const float4*)(pos + (size_t)t * C + c4 * 4);
  float4 o;
  o.x = tv.x + pv.x; o.y = tv.y + pv.y; o.z = tv.z + pv.z; o.w = tv.w + pv.w;
  *(float4*)(x + (size_t)bt * C + c4 * 4) = o;
}

// ---------------------------------------------------------------- layernorm fp32 -> bf16
__global__ __launch_bounds__(256) void k_ln_bf(const float* __restrict__ x, const float* __restrict__ g,
                                               const float* __restrict__ b, __hip_bfloat16* __restrict__ y) {
  int row = blockIdx.x, tid = threadIdx.x;
  float4 v = ((const float4*)(x + (size_t)row * C))[tid];
  float s = v.x + v.y + v.z + v.w;
  float ss = v.x * v.x + v.y * v.y + v.z * v.z + v.w * v.w;
  for (int off = 32; off > 0; off >>= 1) {
    s += __shfl_down(s, off);
    ss += __shfl_down(ss, off);
  }
  __shared__ float sb[4], qb[4];
  int wid = tid >> 6;
  if ((tid & 63) == 0) { sb[wid] = s; qb[wid] = ss; }
  __syncthreads();
  float st = sb[0] + sb[1] + sb[2] + sb[3];
  float qt = qb[0] + qb[1] + qb[2] + qb[3];
  float mean = st * (1.0f / C);
  float var = qt * (1.0f / C) - mean * mean;
  float rstd = rsqrtf(var + 1e-5f);
  float4 gv = ((const float4*)g)[tid];
  float4 bv = ((const float4*)b)[tid];
  union { __hip_bfloat16 h[4]; ushort4 u; } pk;
  pk.h[0] = __float2bfloat16((v.x - mean) * rstd * gv.x + bv.x);
  pk.h[1] = __float2bfloat16((v.y - mean) * rstd * gv.y + bv.y);
  pk.h[2] = __float2bfloat16((v.z - mean) * rstd * gv.z + bv.z);
  pk.h[3] = __float2bfloat16((v.w - mean) * rstd * gv.w + bv.w);
  *(ushort4*)(y + (size_t)row * C + tid * 4) = pk.u;
}

// ---------------------------------------------------------------- generic transpose+convert: in [K][N] f32 -> out [N][K] bf16
__global__ __launch_bounds__(256) void k_transp(const float* __restrict__ in, __hip_bfloat16* __restrict__ out,
                                                int K, int N) {
  __shared__ float t[64][65];
  int n0 = blockIdx.x * 64, k0 = blockIdx.y * 64;
  int tx = threadIdx.x & 15, ty = threadIdx.x >> 4;
#pragma unroll
  for (int i = 0; i < 64; i += 16) {
    float4 v = *(const float4*)(in + (size_t)(k0 + ty + i) * N + n0 + tx * 4);
    t[ty + i][tx * 4 + 0] = v.x;
    t[ty + i][tx * 4 + 1] = v.y;
    t[ty + i][tx * 4 + 2] = v.z;
    t[ty + i][tx * 4 + 3] = v.w;
  }
  __syncthreads();
#pragma unroll
  for (int i = 0; i < 64; i += 16) {
    int n = ty + i;
    union { __hip_bfloat16 h[4]; ushort4 u; } pk;
#pragma unroll
    for (int j = 0; j < 4; ++j) pk.h[j] = __float2bfloat16(t[tx * 4 + j][n]);
    *(ushort4*)(out + (size_t)(n0 + n) * K + k0 + tx * 4) = pk.u;
  }
}

// ---------------------------------------------------------------- qkv weights (H,C,HS) x3 -> [3072][1024] bf16 (row = sel*1024+h*64+s)
__global__ __launch_bounds__(256) void k_prep_qkv(const float* __restrict__ Wq, const float* __restrict__ Wk,
                                                  const float* __restrict__ Wv, __hip_bfloat16* __restrict__ out) {
  int z = blockIdx.y;  // sel*16 + h
  int sel = z >> 4, h = z & 15;
  const float* W = sel == 0 ? Wq : (sel == 1 ? Wk : Wv);
  const float* in = W + (size_t)h * C * HS;                      // [1024][64]
  __hip_bfloat16* o = out + ((size_t)sel * 1024 + h * 64) * C;   // [64][1024]
  __shared__ float t[64][65];
  int k0 = blockIdx.x * 64;
  int tx = threadIdx.x & 15, ty = threadIdx.x >> 4;
#pragma unroll
  for (int i = 0; i < 64; i += 16) {
    float4 v = *(const float4*)(in + (size_t)(k0 + ty + i) * HS + tx * 4);
    t[ty + i][tx * 4 + 0] = v.x;
    t[ty + i][tx * 4 + 1] = v.y;
    t[ty + i][tx * 4 + 2] = v.z;
    t[ty + i][tx * 4 + 3] = v.w;
  }
  __syncthreads();
#pragma unroll
  for (int i = 0; i < 64; i += 16) {
    int n = ty + i;
    union { __hip_bfloat16 h4[4]; ushort4 u; } pk;
#pragma unroll
    for (int j = 0; j < 4; ++j) pk.h4[j] = __float2bfloat16(t[tx * 4 + j][n]);
    *(ushort4*)(o + (size_t)n * C + k0 + tx * 4) = pk.u;
  }
}

// ---------------------------------------------------------------- bias sum over heads
__global__ void k_bsum(const float* __restrict__ phb, float* __restrict__ bs) {
  int c = blockIdx.x * blockDim.x + threadIdx.x;
  if (c < C) {
    float s = 0.0f;
    for (int h = 0; h < H; ++h) s += phb[(size_t)h * C + c];
    bs[c] = s;
  }
}

// ---------------------------------------------------------------- bf16 MFMA GEMM (m97 structure)
// A [M,K] bf16 row-major, Bt [N,K] bf16 row-major; Cm = A @ Bt^T. 128x128 tile, BK=32, 4 waves.
template <int BIAS, int GELU, int RES, int OUTBF>
__global__ __launch_bounds__(256) void k_gemm_bf(const __hip_bfloat16* __restrict__ A,
                                                 const __hip_bfloat16* __restrict__ Bt,
                                                 void* Cout, const float* __restrict__ bias,
                                                 const float* res, int N, int K) {
  __shared__ __align__(16) __hip_bfloat16 As[128 * 32];
  __shared__ __align__(16) __hip_bfloat16 Bs[128 * 32];
  int bm = blockIdx.y * 128, bn = blockIdx.x * 128;
  int tid = threadIdx.x;
  int w = tid >> 6, l = tid & 63;
  int wr = (w >> 1) * 64, wc = (w & 1) * 64;
  int lr = l >> 2;          // staging: row within 16-row segment
  int lk = (l & 3) * 8;     // staging: k offset
  int fr = l & 15;          // fragment row/col within 16
  int fk = (l >> 4) * 8;    // fragment k offset
  const __hip_bfloat16* Ag = A + (size_t)bm * K;
  const __hip_bfloat16* Bg = Bt + (size_t)bn * K;
  f32x4 acc[4][4];
#pragma unroll
  for (int m = 0; m < 4; ++m)
#pragma unroll
    for (int n = 0; n < 4; ++n) acc[m][n] = (f32x4){0.f, 0.f, 0.f, 0.f};

  for (int k0 = 0; k0 < K; k0 += 32) {
    __syncthreads();
#pragma unroll
    for (int i = 0; i < 2; ++i) {
      int seg = w * 2 + i;
      int r = seg * 16 + lr;
      __builtin_amdgcn_global_load_lds(
          (const __attribute__((address_space(1))) void*)(Ag + (size_t)r * K + k0 + lk),
          (__attribute__((address_space(3))) void*)(As + seg * 512), 16, 0, 0);
      __builtin_amdgcn_global_load_lds(
          (const __attribute__((address_space(1))) void*)(Bg + (size_t)r * K + k0 + lk),
          (__attribute__((address_space(3))) void*)(Bs + seg * 512), 16, 0, 0);
    }
    __syncthreads();
    bf16x8 af[4], bfr[4];
#pragma unroll
    for (int m = 0; m < 4; ++m) af[m] = *(const bf16x8*)(As + ((size_t)(wr + m * 16 + fr)) * 32 + fk);
#pragma unroll
    for (int n = 0; n < 4; ++n) bfr[n] = *(const bf16x8*)(Bs + ((size_t)(wc + n * 16 + fr)) * 32 + fk);
#pragma unroll
    for (int m = 0; m < 4; ++m)
#pragma unroll
      for (int n = 0; n < 4; ++n)
        acc[m][n] = __builtin_amdgcn_mfma_f32_16x16x32_bf16(af[m], bfr[n], acc[m][n], 0, 0, 0);
  }
  // epilogue: C/D layout col=lane&15, row=(lane>>4)*4+reg
  int crow0 = (l >> 4) * 4;
  int ccol = l & 15;
#pragma unroll
  for (int m = 0; m < 4; ++m) {
    int row = bm + wr + m * 16 + crow0;
#pragma unroll
    for (int n = 0; n < 4; ++n) {
      int col = bn + wc + n * 16 + ccol;
      float bv = BIAS ? bias[col] : 0.0f;
#pragma unroll
      for (int r = 0; r < 4; ++r) {
        float v = acc[m][n][r] + bv;
        if (GELU) v = 0.5f * v * (1.0f + erff(v * 0.70710678118f));
        if (RES) v += res[(size_t)(row + r) * N + col];
        if (OUTBF)
          ((__hip_bfloat16*)Cout)[(size_t)(row + r) * N + col] = __float2bfloat16(v);
        else
          ((float*)Cout)[(size_t)(row + r) * N + col] = v;
      }
    }
  }
}

// ---------------------------------------------------------------- MFMA flash attention
// qkv: [M,3072] bf16 (q at h*64, k at 1024+h*64, v at 2048+h*64); o: [M,1024] bf16.
// Block = 64 q-rows (4 waves x 16), KV tiles of 32. Wave-parallel online softmax:
// S C-layout row q=(lane>>4)*4+reg lives across the 16 lanes (lane&15) of a group,
// so row-reduce = shfl_xor 1/2/4/8; m/l/alpha stay in the same lanes/regs as the
// O accumulator (same C-layout). P round-trips LDS [16][40] to become an A-frag.
__global__ __launch_bounds__(256) void k_attn(const __hip_bfloat16* __restrict__ qkvh,
                                              __hip_bfloat16* __restrict__ o) {
  const __bf16* qkv = (const __bf16*)qkvh;
  int qi = blockIdx.x;  // q-block of 64 rows
  int bh = blockIdx.y;
  int b = bh >> 4, h = bh & 15;
  int tid = threadIdx.x;
  int w = tid >> 6, l = tid & 63;
  int fr = l & 15, fg = l >> 4;  // fragment lane-row, group
  int qb = qi * 64;
  int qw = qb + w * 16;  // this wave's q base

  __shared__ __align__(16) __bf16 Ks[32][72];  // 144B stride: B-frag reads 2-way (free)
  __shared__ __align__(16) __bf16 Vs[32][76];  // 152B stride: col reads 2-way
  __shared__ __align__(16) __bf16 Ps[4][16][40];

  const size_t bT = (size_t)b * T;
  // Q fragments (A operand), loaded once: row=fr, k=fg*8+j (+32 for second half)
  bf16x8 a_q[2];
  {
    const __bf16* qp = qkv + (bT + qw + fr) * 3072 + h * 64 + fg * 8;
    a_q[0] = *(const bf16x8*)qp;
    a_q[1] = *(const bf16x8*)(qp + 32);
  }
  f32x4 acc_o[4];
#pragma unroll
  for (int n = 0; n < 4; ++n) acc_o[n] = (f32x4){0.f, 0.f, 0.f, 0.f};
  float mrow[4] = {-1e30f, -1e30f, -1e30f, -1e30f};
  float lrow[4] = {0.f, 0.f, 0.f, 0.f};

  int sr = tid >> 3;         // staging row 0..31
  int sc = (tid & 7) * 8;    // staging col base
  int ntile = (qi + 1) * 2;  // causal KV coverage
  for (int t = 0; t < ntile; ++t) {
    int kv0 = t * 32;
    __syncthreads();
    {
      const __bf16* kp = qkv + (bT + kv0 + sr) * 3072 + 1024 + h * 64 + sc;
      bf16x8 k8 = *(const bf16x8*)kp;
      bf16x8 v8 = *(const bf16x8*)(kp + 1024);
      *(bf16x8*)&Ks[sr][sc] = k8;
      *(bf16x4*)&Vs[sr][sc] = __builtin_shufflevector(v8, v8, 0, 1, 2, 3);
      *(bf16x4*)&Vs[sr][sc + 4] = __builtin_shufflevector(v8, v8, 4, 5, 6, 7);
    }
    __syncthreads();
    if (kv0 > qw + 15) continue;  // fully masked for this wave (stay in barrier rhythm)

    // ---- S = scale * Q K^T  (two 16-col kv tiles, k-dim 64 = 2 MFMA each)
    f32x4 s0 = (f32x4){0.f, 0.f, 0.f, 0.f}, s1 = s0;
    s0 = __builtin_amdgcn_mfma_f32_16x16x32_bf16(a_q[0], *(const bf16x8*)&Ks[fr][fg * 8], s0, 0, 0, 0);
    s0 = __builtin_amdgcn_mfma_f32_16x16x32_bf16(a_q[1], *(const bf16x8*)&Ks[fr][32 + fg * 8], s0, 0, 0, 0);
    s1 = __builtin_amdgcn_mfma_f32_16x16x32_bf16(a_q[0], *(const bf16x8*)&Ks[16 + fr][fg * 8], s1, 0, 0, 0);
    s1 = __builtin_amdgcn_mfma_f32_16x16x32_bf16(a_q[1], *(const bf16x8*)&Ks[16 + fr][32 + fg * 8], s1, 0, 0, 0);

    int qrow = qw + fg * 4;  // + r
#pragma unroll
    for (int r = 0; r < 4; ++r) { s0[r] *= 0.03125f; s1[r] *= 0.03125f; }
    if (kv0 + 31 > qw) {  // diagonal tile: per-element causal mask (kv > q -> -inf)
#pragma unroll
      for (int r = 0; r < 4; ++r) {
        if (kv0 + fr > qrow + r) s0[r] = -1e30f;
        if (kv0 + 16 + fr > qrow + r) s1[r] = -1e30f;
      }
    }
    // ---- online softmax (wave-parallel; rows live across 16-lane groups)
    float tm[4], psum[4], alpha[4];
#pragma unroll
    for (int r = 0; r < 4; ++r) tm[r] = fmaxf(s0[r], s1[r]);
#pragma unroll
    for (int off = 1; off < 16; off <<= 1)
#pragma unroll
      for (int r = 0; r < 4; ++r) tm[r] = fmaxf(tm[r], __shfl_xor(tm[r], off));
#pragma unroll
    for (int r = 0; r < 4; ++r) {
      float mnew = fmaxf(mrow[r], tm[r]);
      alpha[r] = __expf(mrow[r] - mnew);
      mrow[r] = mnew;
      float p0 = __expf(s0[r] - mnew);
      float p1 = __expf(s1[r] - mnew);
      s0[r] = p0; s1[r] = p1;
      psum[r] = p0 + p1;
    }
#pragma unroll
    for (int off = 1; off < 16; off <<= 1)
#pragma unroll
      for (int r = 0; r < 4; ++r) psum[r] += __shfl_xor(psum[r], off);
#pragma unroll
    for (int r = 0; r < 4; ++r) lrow[r] = lrow[r] * alpha[r] + psum[r];
#pragma unroll
    for (int n = 0; n < 4; ++n)
#pragma unroll
      for (int r = 0; r < 4; ++r) acc_o[n][r] *= alpha[r];

    // ---- P (C-layout) -> LDS [q][kv] bf16, re-read as A-frag
#pragma unroll
    for (int r = 0; r < 4; ++r) {
      Ps[w][fg * 4 + r][fr] = (__bf16)s0[r];
      Ps[w][fg * 4 + r][16 + fr] = (__bf16)s1[r];
    }
    bf16x8 a_p = *(const bf16x8*)&Ps[w][fr][fg * 8];
    // ---- O += P V   (B-frag: col=d, k=kv -> V column reads)
#pragma unroll
    for (int n = 0; n < 4; ++n) {
      bf16x8 bv;
#pragma unroll
      for (int j = 0; j < 8; ++j) bv[j] = Vs[fg * 8 + j][n * 16 + fr];
      acc_o[n] = __builtin_amdgcn_mfma_f32_16x16x32_bf16(a_p, bv, acc_o[n], 0, 0, 0);
    }
  }
  // ---- epilogue: O /= l, write bf16
  float inv[4];
#pragma unroll
  for (int r = 0; r < 4; ++r) inv[r] = 1.0f / lrow[r];
  __bf16* ob = (__bf16*)o;
#pragma unroll
  for (int n = 0; n < 4; ++n)
#pragma unroll
    for (int r = 0; r < 4; ++r)
      ob[(bT + qw + fg * 4 + r) * 1024 + h * 64 + n * 16 + fr] = (__bf16)(acc_o[n][r] * inv[r]);
}

// ---------------------------------------------------------------- launch
extern "C" void kernel_launch(void* const* d_in, const int* in_sizes, int n_in,
                              void* d_out, int out_size, void* d_ws, size_t ws_size,
                              hipStream_t stream) {
  const int* idx = (const int*)d_in[0];
  const float* tok = (const float*)d_in[1];
  const float* pos = (const float*)d_in[2];
  const float* Wq = (const float*)d_in[3];
  const float* Wk = (const float*)d_in[4];
  const float* Wv = (const float*)d_in[5];
  const float* Phw = (const float*)d_in[6];
  const float* Phb = (const float*)d_in[7];
  const float* Pmw = (const float*)d_in[8];
  const float* Pmb = (const float*)d_in[9];
  const float* ln1g = (const float*)d_in[10];
  const float* ln1b = (const float*)d_in[11];
  const float* ln2g = (const float*)d_in[12];
  const float* ln2b = (const float*)d_in[13];
  const float* W1 = (const float*)d_in[14];
  const float* b1 = (const float*)d_in[15];
  const float* W2 = (const float*)d_in[16];
  const float* b2 = (const float*)d_in[17];
  const float* lnfg = (const float*)d_in[18];
  const float* lnfb = (const float*)d_in[19];
  const float* headw = (const float*)d_in[20];
  const float* headb = (const float*)d_in[21];
  float* out = (float*)d_out;

  // Workspace layout (peak ~109 MB):
  //   x (fp32 residual) | bsum | [qkvb ob sa hb wt] (per-layer, contiguous 84MB) | xn
  // Head-weight transpose (64 MB) aliases the dead per-layer region.
  char* p = (char*)d_ws;
  float* x = (float*)p;                       p += (size_t)M * C * 4;
  float* bsumv = (float*)p;                   p += (size_t)C * 4;
  char* layer_region = p;
  __hip_bfloat16* qkvb = (__hip_bfloat16*)p;  p += (size_t)M * 3072 * 2;
  __hip_bfloat16* ob = (__hip_bfloat16*)p;    p += (size_t)M * C * 2;
  __hip_bfloat16* sa = (__hip_bfloat16*)p;    p += (size_t)M * C * 2;
  __hip_bfloat16* hb = (__hip_bfloat16*)p;    p += (size_t)M * 4 * C * 2;
  __hip_bfloat16* wt = (__hip_bfloat16*)p;    p += (size_t)4 * C * C * 2;  // per-layer weight scratch
  __hip_bfloat16* xn = (__hip_bfloat16*)p;    p += (size_t)M * C * 2;
  __hip_bfloat16* wt_head = (__hip_bfloat16*)layer_region;  // [V,C] bf16, aliases dead buffers

  k_embed<<<(M * C / 4 + 255) / 256, 256, 0, stream>>>(idx, tok, pos, x);

  for (int l = 0; l < NL; ++l) {
    // ln1 -> xn (bf16)
    k_ln_bf<<<M, 256, 0, stream>>>(x, ln1g + (size_t)l * C, ln1b + (size_t)l * C, xn);
    // qkv weights -> wt [3072][1024]
    k_prep_qkv<<<dim3(16, 48), 256, 0, stream>>>(Wq + (size_t)l * H * C * HS, Wk + (size_t)l * H * C * HS,
                                                 Wv + (size_t)l * H * C * HS, wt);
    // qkv = xn @ wt^T -> bf16 [M,3072]
    k_gemm_bf<0, 0, 0, 1><<<dim3(3072 / 128, M / 128), 256, 0, stream>>>(xn, wt, qkvb, nullptr, nullptr, 3072, C);
    // attention -> ob (bf16)
    k_attn<<<dim3(T / 64, B * H), 256, 0, stream>>>(qkvb, ob);
    // per-head proj bias summed over heads
    k_bsum<<<(C + 255) / 256, 256, 0, stream>>>(Phb + (size_t)l * H * C, bsumv);
    // Ph_w [1024,1024] -> wt^T
    k_transp<<<dim3(16, 16), 256, 0, stream>>>(Phw + (size_t)l * H * HS * C, wt, C, C);
    // sa = ob @ Phw + bsum -> bf16
    k_gemm_bf<1, 0, 0, 1><<<dim3(C / 128, M / 128), 256, 0, stream>>>(ob, wt, sa, bsumv, nullptr, C, C);
    // Pm_w -> wt^T
    k_transp<<<dim3(16, 16), 256, 0, stream>>>(Pmw + (size_t)l * C * C, wt, C, C);
    // x = x + sa @ Pmw + Pmb  (fp32 residual)
    k_gemm_bf<1, 0, 1, 0><<<dim3(C / 128, M / 128), 256, 0, stream>>>(sa, wt, x, Pmb + (size_t)l * C, x, C, C);
    // ln2 -> xn
    k_ln_bf<<<M, 256, 0, stream>>>(x, ln2g + (size_t)l * C, ln2b + (size_t)l * C, xn);
    // W1 [1024,4096] -> wt^T
    k_transp<<<dim3(64, 16), 256, 0, stream>>>(W1 + (size_t)l * C * 4 * C, wt, C, 4 * C);
    // h = gelu(xn @ W1 + b1) -> bf16 [M,4096]
    k_gemm_bf<1, 1, 0, 1><<<dim3(4 * C / 128, M / 128), 256, 0, stream>>>(xn, wt, hb, b1 + (size_t)l * 4 * C, nullptr, 4 * C, C);
    // W2 [4096,1024] -> wt^T
    k_transp<<<dim3(16, 64), 256, 0, stream>>>(W2 + (size_t)l * 4 * C * C, wt, 4 * C, C);
    // x = x + h @ W2 + b2
    k_gemm_bf<1, 0, 1, 0><<<dim3(C / 128, M / 128), 256, 0, stream>>>(hb, wt, x, b2 + (size_t)l * C, x, C, 4 * C);
  }

  // final LN + head (head weight transpose reuses the dead per-layer region)
  k_ln_bf<<<M, 256, 0, stream>>>(x, lnfg, lnfb, xn);
  k_transp<<<dim3(500, 16), 256, 0, stream>>>(headw, wt_head, C, V);
  k_gemm_bf<1, 0, 0, 0><<<dim3(V / 128, M / 128), 256, 0, stream>>>(xn, wt_head, out, headb, nullptr, V, C);
}